// Round 8
// baseline (1188.102 us; speedup 1.0000x reference)
//
#include <hip/hip_runtime.h>
#include <hip/hip_bf16.h>

#define ALPHA_F 0.1f
#define KSTEPS 10
#define BKT_SH 9                       // 512 dst rows per bucket
#define P1_CHUNK 8192
#define MAXPAD_PER_BUCKET (512 * 16)   // rows padded to mult-of-16

typedef __attribute__((ext_vector_type(8))) short bf16x8;
typedef __attribute__((ext_vector_type(4))) float f32x4;

__device__ __forceinline__ unsigned short f2bf(float f) {
  union { float f; unsigned int u; } v; v.f = f;
  unsigned int u = v.u;
  u += 0x7FFFu + ((u >> 16) & 1u);   // round-to-nearest-even
  return (unsigned short)(u >> 16);
}
__device__ __forceinline__ float bflo(unsigned int u) { return __uint_as_float(u << 16); }
__device__ __forceinline__ float bfhi(unsigned int u) { return __uint_as_float(u & 0xFFFF0000u); }

__device__ __forceinline__ void gload16(const void* g, void* l) {
  __builtin_amdgcn_global_load_lds(
      (const __attribute__((address_space(1))) void*)g,
      (__attribute__((address_space(3))) void*)l, 16, 0, 0);
}

// ============ CSR build: two-level binned counting sort, packed tmp, pad-16 rows ============

__global__ __launch_bounds__(256)
void p0_hist(const int* __restrict__ dstv, int E, int* __restrict__ bhist) {
  __shared__ int h[256];
  int t = threadIdx.x;
  h[t] = 0;
  __syncthreads();
  int b0 = blockIdx.x * P1_CHUNK;
  int lim = min(P1_CHUNK, E - b0);
  for (int i = t; i < lim; i += 256) atomicAdd(&h[dstv[b0 + i] >> BKT_SH], 1);
  __syncthreads();
  if (h[t]) atomicAdd(&bhist[t], h[t]);
}

__global__ void p0_scan(const int* __restrict__ bhist, int* __restrict__ bbase,
                        int* __restrict__ gcur) {
  __shared__ int s[256];
  int t = threadIdx.x;
  int mine = bhist[t];
  s[t] = mine;
  __syncthreads();
  for (int off = 1; off < 256; off <<= 1) {
    int v = (t >= off) ? s[t - off] : 0;
    __syncthreads();
    s[t] += v;
    __syncthreads();
  }
  int excl = s[t] - mine;
  bbase[t] = excl;
  gcur[t] = excl;
}

// p1: scatter PACKED (src<<9 | dst&511) into bucket-contiguous tmp
__global__ __launch_bounds__(256)
void p1_scatter(const int* __restrict__ srcv, const int* __restrict__ dstv, int E,
                int* __restrict__ gcur, int* __restrict__ tmp) {
  __shared__ int h[256];
  __shared__ int loc[256];
  int t = threadIdx.x;
  int b0 = blockIdx.x * P1_CHUNK;
  int lim = min(P1_CHUNK, E - b0);
  h[t] = 0;
  __syncthreads();
  for (int i = t; i < lim; i += 256) atomicAdd(&h[dstv[b0 + i] >> BKT_SH], 1);
  __syncthreads();
  loc[t] = h[t] ? atomicAdd(&gcur[t], h[t]) : 0;
  __syncthreads();
  h[t] = 0;
  __syncthreads();
  for (int i = t; i < lim; i += 256) {
    int d = dstv[b0 + i], s = srcv[b0 + i];
    int b = d >> BKT_SH;
    int pos = loc[b] + atomicAdd(&h[b], 1);
    tmp[pos] = (s << BKT_SH) | (d & 511);
  }
}

// p2: one block per bucket — counts, dis, PADDED rowptr (mult-of-16), col scatter + pad fill
__global__ __launch_bounds__(256)
void p2_bucket(const int* __restrict__ tmp, const int* __restrict__ bbase,
               const int* __restrict__ bhist, int* __restrict__ counts,
               float* __restrict__ dis, int* __restrict__ rowptr,
               int* __restrict__ col, int N) {
  __shared__ int h1[512];
  __shared__ int cur[512];
  __shared__ int s2[256];
  const int t = threadIdx.x;
  const int b = blockIdx.x;
  const int base = bbase[b];
  const int pbase = base + b * MAXPAD_PER_BUCKET;
  const int sz = bhist[b];
  const int r0 = b << BKT_SH;
  const int nrows = min(512, N - r0);

  h1[t] = 0; h1[t + 256] = 0;
  __syncthreads();
  for (int i = t; i < sz; i += 256) atomicAdd(&h1[tmp[base + i] & 511], 1);
  __syncthreads();
  int a = (h1[2 * t] + 15) & ~15;
  int c = (h1[2 * t + 1] + 15) & ~15;
  s2[t] = a + c;
  __syncthreads();
  for (int off = 1; off < 256; off <<= 1) {
    int v = (t >= off) ? s2[t - off] : 0;
    __syncthreads();
    s2[t] += v;
    __syncthreads();
  }
  int excl2 = s2[t] - (a + c);
  cur[2 * t] = excl2;
  cur[2 * t + 1] = excl2 + a;
  __syncthreads();
  if (t < nrows) {
    rowptr[r0 + t] = pbase + cur[t];
    counts[r0 + t] = h1[t];
    dis[r0 + t] = rsqrtf((float)(h1[t] + 1));
  }
  if (t + 256 < nrows) {
    rowptr[r0 + t + 256] = pbase + cur[t + 256];
    counts[r0 + t + 256] = h1[t + 256];
    dis[r0 + t + 256] = rsqrtf((float)(h1[t + 256] + 1));
  }
  __syncthreads();
  for (int i = t; i < sz; i += 256) {
    int u = tmp[base + i];
    int p = pbase + atomicAdd(&cur[u & 511], 1);
    col[p] = u >> BKT_SH;
  }
  __syncthreads();
  for (int i = t; i < nrows; i += 256) {
    int cnt = h1[i];
    int c16 = (cnt + 15) & ~15;
    int ps = pbase + cur[i];
    for (int k = cnt; k < c16; ++k) col[ps++] = N;
  }
}

// zero pad row N of both y buffers (both halves): y [2][N+1][32]
__global__ void k_zrow(unsigned short* __restrict__ yA, unsigned short* __restrict__ yB, int N) {
  int t = threadIdx.x;                 // 128 threads
  size_t N1 = (size_t)N + 1;
  if (t < 64) yA[((size_t)(t >> 5) * N1 + N) * 32 + (t & 31)] = 0;
  else { int u = t - 64; yB[((size_t)(u >> 5) * N1 + N) * 32 + (u & 31)] = 0; }
}

// ============ weight conversion to MFMA-native tiled layouts ============
// W1 [512][256] -> WT1t: [kstep8][nsub16][q8][n16][e8]
__global__ void k_wconv1(const float* __restrict__ W, unsigned short* __restrict__ WT) {
  int idx = blockIdx.x * 256 + threadIdx.x;
  if (idx >= 512 * 256) return;
  int e = idx & 7, n = (idx >> 3) & 15, q = (idx >> 7) & 7;
  int nsub = (idx >> 10) & 15, kstep = idx >> 14;
  int k = kstep * 64 + q * 8 + e;
  int ncol = nsub * 16 + n;
  WT[idx] = f2bf(W[(size_t)k * 256 + ncol]);
}

// W2 [256][64] -> WT2t: [kstep4][nsub4][q8][n16][e8]
__global__ void k_wconv2(const float* __restrict__ W, unsigned short* __restrict__ WT) {
  int idx = blockIdx.x * 256 + threadIdx.x;
  if (idx >= 256 * 64) return;
  int e = idx & 7, n = (idx >> 3) & 15, q = (idx >> 7) & 7;
  int nsub = (idx >> 10) & 3, kstep = idx >> 12;
  int k = kstep * 64 + q * 8 + e;
  int ncol = nsub * 16 + n;
  WT[idx] = f2bf(W[(size_t)k * 64 + ncol]);
}

// ============ GEMM1: hid_tiled = relu(x @ W1 + b1), BM=128 BN=256 BK=64 ============
__global__ __launch_bounds__(512)
void gemm1_kernel(const float* __restrict__ X, const unsigned short* __restrict__ Bt,
                  const float* __restrict__ bias, unsigned short* __restrict__ outT,
                  int M) {
  __shared__ __align__(16) unsigned short Al[8192];    // 16 KB
  __shared__ __align__(16) unsigned short Bl[16384];   // 32 KB
  const int t = threadIdx.x;
  const int m0 = blockIdx.x * 128;
  const int lane = t & 63;
  const int w = t >> 6;
  const int wm = w >> 2, wn = w & 3;

  const int sm = ((t >> 7) << 4) + (t & 15);
  const int sq = (t >> 4) & 7;
  const int r1 = m0 + sm;
  const int r2 = r1 + 64;
  const bool g1 = r1 < M, g2 = r2 < M;

  f32x4 acc[4][4] = {};

  for (int ks = 0; ks < 8; ++ks) {
    const int kc = ks * 64 + sq * 8;
    uint4 v1 = {0, 0, 0, 0}, v2 = {0, 0, 0, 0};
    if (g1) {
      const float* p = X + (size_t)r1 * 512 + kc;
      float4 a = *(const float4*)p, b = *(const float4*)(p + 4);
      unsigned short* o = (unsigned short*)&v1;
      o[0] = f2bf(a.x); o[1] = f2bf(a.y); o[2] = f2bf(a.z); o[3] = f2bf(a.w);
      o[4] = f2bf(b.x); o[5] = f2bf(b.y); o[6] = f2bf(b.z); o[7] = f2bf(b.w);
    }
    if (g2) {
      const float* p = X + (size_t)r2 * 512 + kc;
      float4 a = *(const float4*)p, b = *(const float4*)(p + 4);
      unsigned short* o = (unsigned short*)&v2;
      o[0] = f2bf(a.x); o[1] = f2bf(a.y); o[2] = f2bf(a.z); o[3] = f2bf(a.w);
      o[4] = f2bf(b.x); o[5] = f2bf(b.y); o[6] = f2bf(b.z); o[7] = f2bf(b.w);
    }
    *(uint4*)&Al[t * 8] = v1;
    *(uint4*)&Al[(t + 512) * 8] = v2;

    const unsigned short* bs = Bt + ks * 16384;
    gload16(bs + (size_t)t * 8,          &Bl[t * 8]);
    gload16(bs + (size_t)(t + 512) * 8,  &Bl[(t + 512) * 8]);
    gload16(bs + (size_t)(t + 1024) * 8, &Bl[(t + 1024) * 8]);
    gload16(bs + (size_t)(t + 1536) * 8, &Bl[(t + 1536) * 8]);
    __syncthreads();

#pragma unroll
    for (int kk = 0; kk < 2; ++kk) {
      bf16x8 af[4], bfv[4];
#pragma unroll
      for (int mi = 0; mi < 4; ++mi)
        af[mi] = *(const bf16x8*)&Al[((wm * 4 + mi) * 128 + kk * 64 + (lane >> 4) * 16 + (lane & 15)) * 8];
#pragma unroll
      for (int ni = 0; ni < 4; ++ni)
        bfv[ni] = *(const bf16x8*)&Bl[((wn * 4 + ni) * 128 + kk * 64 + (lane >> 4) * 16 + (lane & 15)) * 8];
#pragma unroll
      for (int mi = 0; mi < 4; ++mi)
#pragma unroll
        for (int ni = 0; ni < 4; ++ni)
          acc[mi][ni] = __builtin_amdgcn_mfma_f32_16x16x32_bf16(af[mi], bfv[ni], acc[mi][ni], 0, 0, 0);
    }
    __syncthreads();
  }

  unsigned short* ob = outT + (size_t)blockIdx.x * 32768;
#pragma unroll
  for (int mi = 0; mi < 4; ++mi) {
#pragma unroll
    for (int ni = 0; ni < 4; ++ni) {
      int n = wn * 64 + ni * 16 + (lane & 15);
      float bv = bias[n];
      int kstep = n >> 6, q = (n >> 3) & 7, e = n & 7;
#pragma unroll
      for (int j = 0; j < 4; ++j) {
        int lm = wm * 64 + mi * 16 + (lane >> 4) * 4 + j;
        if (m0 + lm < M) {
          float v = fmaxf(acc[mi][ni][j] + bv, 0.f);
          int msub = lm >> 4, mm = lm & 15;
          ob[((((kstep * 8 + msub) * 8 + q) * 16 + mm) * 8) + e] = f2bf(v);
        }
      }
    }
  }
}

// ============ GEMM2: halved hb [2][N][32] and y0 = bf16(dis*h) [2][N+1][32] ============
__global__ __launch_bounds__(256)
void gemm2_kernel(const unsigned short* __restrict__ At, const unsigned short* __restrict__ Bt,
                  const float* __restrict__ bias, const float* __restrict__ dis,
                  unsigned short* __restrict__ hb, unsigned short* __restrict__ y0, int M) {
  __shared__ __align__(16) unsigned short Al[8192];
  __shared__ __align__(16) unsigned short Bl[4096];
  const int t = threadIdx.x;
  const int m0 = blockIdx.x * 128;
  const int lane = t & 63;
  const int w = t >> 6;
  const int wm = w >> 1, wn = w & 1;
  const size_t N1 = (size_t)M + 1;

  f32x4 acc[4][2] = {};

  const unsigned short* ab = At + (size_t)blockIdx.x * 32768;
  for (int ks = 0; ks < 4; ++ks) {
    const unsigned short* as = ab + ks * 8192;
    gload16(as + (size_t)t * 8,         &Al[t * 8]);
    gload16(as + (size_t)(t + 256) * 8, &Al[(t + 256) * 8]);
    gload16(as + (size_t)(t + 512) * 8, &Al[(t + 512) * 8]);
    gload16(as + (size_t)(t + 768) * 8, &Al[(t + 768) * 8]);
    const unsigned short* bs = Bt + ks * 4096;
    gload16(bs + (size_t)t * 8,         &Bl[t * 8]);
    gload16(bs + (size_t)(t + 256) * 8, &Bl[(t + 256) * 8]);
    __syncthreads();

#pragma unroll
    for (int kk = 0; kk < 2; ++kk) {
      bf16x8 af[4], bfv[2];
#pragma unroll
      for (int mi = 0; mi < 4; ++mi)
        af[mi] = *(const bf16x8*)&Al[((wm * 4 + mi) * 128 + kk * 64 + (lane >> 4) * 16 + (lane & 15)) * 8];
#pragma unroll
      for (int ni = 0; ni < 2; ++ni)
        bfv[ni] = *(const bf16x8*)&Bl[((wn * 2 + ni) * 128 + kk * 64 + (lane >> 4) * 16 + (lane & 15)) * 8];
#pragma unroll
      for (int mi = 0; mi < 4; ++mi)
#pragma unroll
        for (int ni = 0; ni < 2; ++ni)
          acc[mi][ni] = __builtin_amdgcn_mfma_f32_16x16x32_bf16(af[mi], bfv[ni], acc[mi][ni], 0, 0, 0);
    }
    __syncthreads();
  }

#pragma unroll
  for (int mi = 0; mi < 4; ++mi) {
#pragma unroll
    for (int ni = 0; ni < 2; ++ni) {
      int gn = wn * 32 + ni * 16 + (lane & 15);
      float bv = bias[gn];
      int hh = gn >> 5, cc = gn & 31;
#pragma unroll
      for (int j = 0; j < 4; ++j) {
        int gm = m0 + wm * 64 + mi * 16 + (lane >> 4) * 4 + j;
        if (gm < M) {
          float v = acc[mi][ni][j] + bv;
          hb[((size_t)hh * M + gm) * 32 + cc] = f2bf(v);
          y0[((size_t)hh * N1 + gm) * 32 + cc] = f2bf(dis[gm] * v);
        }
      }
    }
  }
}

// ============ halved PPR step: half h pinned to XCDs {4h..4h+3} ============
// y [2][N+1][32] bf16 (row N zero). 16 groups x 4 lanes; 16B gather per lane;
// 16 edges/iter, rows padded to 16 (pad col = N).
template<bool FINAL>
__global__ __launch_bounds__(256)
void prop_kernel(const unsigned short* __restrict__ yin,
                 const unsigned short* __restrict__ hbh,
                 void* __restrict__ yout,
                 const int* __restrict__ rowptr, const int* __restrict__ counts,
                 const int* __restrict__ col, const float* __restrict__ dis,
                 int N, int G) {
  const int bid = blockIdx.x;
  const int xcd = bid & 7;
  const int h = xcd >> 2;
  const int i = (bid >> 3) * 4 + (xcd & 3);
  if (i >= G) return;
  int r = i * 4 + (threadIdx.x >> 6);
  if (r >= N) return;
  r = __builtin_amdgcn_readfirstlane(r);
  const int lane = threadIdx.x & 63;
  const int g = lane >> 2;           // 16 edge groups
  const int sl = lane & 3;           // 16B col slice
  const size_t N1 = (size_t)N + 1;
  const unsigned short* yq = yin + (size_t)h * N1 * 32;

  const int start = rowptr[r];
  const int iters = (counts[r] + 15) >> 4;
  const float dr = dis[r];
  uint4 zs = *(const uint4*)(yq + (size_t)r * 32 + sl * 8);
  uint4 hr = *(const uint4*)(hbh + ((size_t)h * N + r) * 32 + sl * 8);

  float acc[8] = {0.f, 0.f, 0.f, 0.f, 0.f, 0.f, 0.f, 0.f};
  const int* cp = col + start + g;
  for (int it = 0; it < iters; ++it) {
    int c = cp[it * 16];
    uint4 z = *(const uint4*)(yq + (size_t)c * 32 + sl * 8);
    acc[0] += bflo(z.x); acc[1] += bfhi(z.x);
    acc[2] += bflo(z.y); acc[3] += bfhi(z.y);
    acc[4] += bflo(z.z); acc[5] += bfhi(z.z);
    acc[6] += bflo(z.w); acc[7] += bfhi(z.w);
  }
  // reduce across 16 groups (lane bits 2..5)
#pragma unroll
  for (int k = 0; k < 8; ++k) {
    acc[k] += __shfl_xor(acc[k], 4);
    acc[k] += __shfl_xor(acc[k], 8);
    acc[k] += __shfl_xor(acc[k], 16);
    acc[k] += __shfl_xor(acc[k], 32);
  }

  float selfz[8] = { bflo(zs.x), bfhi(zs.x), bflo(zs.y), bfhi(zs.y),
                     bflo(zs.z), bfhi(zs.z), bflo(zs.w), bfhi(zs.w) };
  float hv[8]    = { bflo(hr.x), bfhi(hr.x), bflo(hr.y), bfhi(hr.y),
                     bflo(hr.z), bfhi(hr.z), bflo(hr.w), bfhi(hr.w) };
  float f[8];
#pragma unroll
  for (int k = 0; k < 8; ++k)
    f[k] = ALPHA_F * hv[k] + (1.f - ALPHA_F) * dr * (acc[k] + selfz[k]);

  if (!FINAL) {
    if (g == 0) {
      uint4 o;
      o.x = (unsigned)f2bf(dr * f[0]) | ((unsigned)f2bf(dr * f[1]) << 16);
      o.y = (unsigned)f2bf(dr * f[2]) | ((unsigned)f2bf(dr * f[3]) << 16);
      o.z = (unsigned)f2bf(dr * f[4]) | ((unsigned)f2bf(dr * f[5]) << 16);
      o.w = (unsigned)f2bf(dr * f[6]) | ((unsigned)f2bf(dr * f[7]) << 16);
      *(uint4*)((unsigned short*)yout + ((size_t)h * N1 + r) * 32 + sl * 8) = o;
    }
  } else {
    // write f32 into d_out row-major [N][64]; k_lsm finishes in-place
    if (g == 0) {
      float* op = (float*)yout + (size_t)r * 64 + h * 32 + sl * 8;
      *(float4*)op       = make_float4(f[0], f[1], f[2], f[3]);
      *(float4*)(op + 4) = make_float4(f[4], f[5], f[6], f[7]);
    }
  }
}

// in-place log_softmax on d_out [N][64]
__global__ __launch_bounds__(256)
void k_lsm(float* __restrict__ z, int N) {
  int r = (blockIdx.x * 256 + threadIdx.x) >> 6;
  if (r >= N) return;
  int lane = threadIdx.x & 63;
  float v = z[(size_t)r * 64 + lane];
  float m = v;
#pragma unroll
  for (int off = 32; off; off >>= 1) m = fmaxf(m, __shfl_xor(m, off));
  float e = __expf(v - m);
  float s = e;
#pragma unroll
  for (int off = 32; off; off >>= 1) s += __shfl_xor(s, off);
  z[(size_t)r * 64 + lane] = v - m - __logf(s);
}

extern "C" void kernel_launch(void* const* d_in, const int* in_sizes, int n_in,
                              void* d_out, int out_size, void* d_ws, size_t ws_size,
                              hipStream_t stream) {
  const float* x  = (const float*)d_in[0];
  const int*   ei = (const int*)d_in[1];
  const float* W1 = (const float*)d_in[2];
  const float* b1 = (const float*)d_in[3];
  const float* W2 = (const float*)d_in[4];
  const float* b2 = (const float*)d_in[5];

  const int IN = 512, HID = 256, OUT = 64;
  const int N = in_sizes[0] / IN;
  const int E = in_sizes[1] / 2;
  const int* srcv = ei;
  const int* dstv = ei + E;
  const int NBUCK = (N + (1 << BKT_SH) - 1) >> BKT_SH;
  const int MT = (N + 127) / 128;
  const size_t N1 = (size_t)N + 1;

  char* p = (char*)d_ws;
  auto alloc = [&](size_t bytes) -> void* {
    void* r = (void*)p;
    p += (bytes + 255) & ~(size_t)255;
    return r;
  };
  int*   bhist  = (int*)alloc(256 * 4);
  int*   bbase  = (int*)alloc(256 * 4);
  int*   gcur   = (int*)alloc(256 * 4);
  int*   counts = (int*)alloc((size_t)N * 4);
  float* dis    = (float*)alloc((size_t)N * 4);
  int*   rowptr = (int*)alloc((size_t)N * 4);
  int*   col    = (int*)alloc(((size_t)E + 256 * MAXPAD_PER_BUCKET) * 4);
  unsigned short* WT1t = (unsigned short*)alloc((size_t)IN * HID * 2);
  unsigned short* WT2t = (unsigned short*)alloc((size_t)HID * OUT * 2);
  unsigned short* hb   = (unsigned short*)alloc((size_t)N * OUT * 2);    // [2][N][32]
  unsigned short* yA   = (unsigned short*)alloc(N1 * OUT * 2);           // [2][N+1][32]
  unsigned short* yBs  = (unsigned short*)alloc(N1 * OUT * 2);           // [2][N+1][32]
  // region R: tmp (build, int E) -> hidT (gemm)
  size_t hidT_bytes = (size_t)MT * 32768 * 2;
  size_t R_bytes = hidT_bytes;
  if ((size_t)E * 4 > R_bytes) R_bytes = (size_t)E * 4;
  char* R = (char*)alloc(R_bytes);
  int* tmp = (int*)R;
  unsigned short* hidT = (unsigned short*)R;

  hipMemsetAsync(bhist, 0, 256 * 4, stream);

  const int p1blocks = (E + P1_CHUNK - 1) / P1_CHUNK;
  p0_hist<<<p1blocks, 256, 0, stream>>>(dstv, E, bhist);
  p0_scan<<<1, 256, 0, stream>>>(bhist, bbase, gcur);
  p1_scatter<<<p1blocks, 256, 0, stream>>>(srcv, dstv, E, gcur, tmp);
  p2_bucket<<<NBUCK, 256, 0, stream>>>(tmp, bbase, bhist, counts, dis, rowptr, col, N);

  k_wconv1<<<(IN * HID + 255) / 256, 256, 0, stream>>>(W1, WT1t);
  k_wconv2<<<(HID * OUT + 255) / 256, 256, 0, stream>>>(W2, WT2t);

  gemm1_kernel<<<MT, 512, 0, stream>>>(x, WT1t, b1, hidT, N);
  gemm2_kernel<<<MT, 256, 0, stream>>>(hidT, WT2t, b2, dis, hb, yA, N);
  k_zrow<<<1, 128, 0, stream>>>(yA, yBs, N);

  const int G = (N + 3) / 4;
  const int pgrid = 8 * ((G + 3) / 4);
  const unsigned short* ycur = yA;
  for (int it = 0; it < KSTEPS - 1; ++it) {
    unsigned short* ynext = (it & 1) ? yA : yBs;
    prop_kernel<false><<<pgrid, 256, 0, stream>>>(ycur, hb, ynext, rowptr, counts, col, dis, N, G);
    ycur = ynext;
  }
  prop_kernel<true><<<pgrid, 256, 0, stream>>>(ycur, hb, d_out, rowptr, counts, col, dis, N, G);
  k_lsm<<<(N + 3) / 4, 256, 0, stream>>>((float*)d_out, N);
}

// Round 9
// 758.215 us; speedup vs baseline: 1.5670x; 1.5670x over previous
//
#include <hip/hip_runtime.h>
#include <hip/hip_bf16.h>

#define ALPHA_F 0.1f
#define KSTEPS 10
#define BKT_SH 9                       // 512 dst rows per bucket
#define P1_CHUNK 8192
#define MAXPAD_PER_BUCKET (512 * 32)   // rows padded to mult-of-32

typedef __attribute__((ext_vector_type(8))) short bf16x8;
typedef __attribute__((ext_vector_type(4))) float f32x4;

__device__ __forceinline__ unsigned short f2bf(float f) {
  union { float f; unsigned int u; } v; v.f = f;
  unsigned int u = v.u;
  u += 0x7FFFu + ((u >> 16) & 1u);   // round-to-nearest-even
  return (unsigned short)(u >> 16);
}
__device__ __forceinline__ float bflo(unsigned int u) { return __uint_as_float(u << 16); }
__device__ __forceinline__ float bfhi(unsigned int u) { return __uint_as_float(u & 0xFFFF0000u); }

__device__ __forceinline__ void gload16(const void* g, void* l) {
  __builtin_amdgcn_global_load_lds(
      (const __attribute__((address_space(1))) void*)g,
      (__attribute__((address_space(3))) void*)l, 16, 0, 0);
}

// ============ CSR build: two-level binned counting sort, packed tmp, pad-32 rows ============

__global__ __launch_bounds__(256)
void p0_hist(const int* __restrict__ dstv, int E, int* __restrict__ bhist) {
  __shared__ int h[256];
  int t = threadIdx.x;
  h[t] = 0;
  __syncthreads();
  int b0 = blockIdx.x * P1_CHUNK;
  int lim = min(P1_CHUNK, E - b0);
  for (int i = t; i < lim; i += 256) atomicAdd(&h[dstv[b0 + i] >> BKT_SH], 1);
  __syncthreads();
  if (h[t]) atomicAdd(&bhist[t], h[t]);
}

__global__ void p0_scan(const int* __restrict__ bhist, int* __restrict__ bbase,
                        int* __restrict__ gcur) {
  __shared__ int s[256];
  int t = threadIdx.x;
  int mine = bhist[t];
  s[t] = mine;
  __syncthreads();
  for (int off = 1; off < 256; off <<= 1) {
    int v = (t >= off) ? s[t - off] : 0;
    __syncthreads();
    s[t] += v;
    __syncthreads();
  }
  int excl = s[t] - mine;
  bbase[t] = excl;
  gcur[t] = excl;
}

// p1: scatter PACKED (src<<9 | dst&511) into bucket-contiguous tmp
__global__ __launch_bounds__(256)
void p1_scatter(const int* __restrict__ srcv, const int* __restrict__ dstv, int E,
                int* __restrict__ gcur, int* __restrict__ tmp) {
  __shared__ int h[256];
  __shared__ int loc[256];
  int t = threadIdx.x;
  int b0 = blockIdx.x * P1_CHUNK;
  int lim = min(P1_CHUNK, E - b0);
  h[t] = 0;
  __syncthreads();
  for (int i = t; i < lim; i += 256) atomicAdd(&h[dstv[b0 + i] >> BKT_SH], 1);
  __syncthreads();
  loc[t] = h[t] ? atomicAdd(&gcur[t], h[t]) : 0;
  __syncthreads();
  h[t] = 0;
  __syncthreads();
  for (int i = t; i < lim; i += 256) {
    int d = dstv[b0 + i], s = srcv[b0 + i];
    int b = d >> BKT_SH;
    int pos = loc[b] + atomicAdd(&h[b], 1);
    tmp[pos] = (s << BKT_SH) | (d & 511);
  }
}

// p2: one block per bucket — counts, dis, PADDED rowptr (mult-of-32), col scatter + pad fill
__global__ __launch_bounds__(256)
void p2_bucket(const int* __restrict__ tmp, const int* __restrict__ bbase,
               const int* __restrict__ bhist, int* __restrict__ counts,
               float* __restrict__ dis, int* __restrict__ rowptr,
               int* __restrict__ col, int N) {
  __shared__ int h1[512];
  __shared__ int cur[512];
  __shared__ int s2[256];
  const int t = threadIdx.x;
  const int b = blockIdx.x;
  const int base = bbase[b];
  const int pbase = base + b * MAXPAD_PER_BUCKET;
  const int sz = bhist[b];
  const int r0 = b << BKT_SH;
  const int nrows = min(512, N - r0);

  h1[t] = 0; h1[t + 256] = 0;
  __syncthreads();
  for (int i = t; i < sz; i += 256) atomicAdd(&h1[tmp[base + i] & 511], 1);
  __syncthreads();
  int a = (h1[2 * t] + 31) & ~31;
  int c = (h1[2 * t + 1] + 31) & ~31;
  s2[t] = a + c;
  __syncthreads();
  for (int off = 1; off < 256; off <<= 1) {
    int v = (t >= off) ? s2[t - off] : 0;
    __syncthreads();
    s2[t] += v;
    __syncthreads();
  }
  int excl2 = s2[t] - (a + c);
  cur[2 * t] = excl2;
  cur[2 * t + 1] = excl2 + a;
  __syncthreads();
  if (t < nrows) {
    rowptr[r0 + t] = pbase + cur[t];
    counts[r0 + t] = h1[t];
    dis[r0 + t] = rsqrtf((float)(h1[t] + 1));
  }
  if (t + 256 < nrows) {
    rowptr[r0 + t + 256] = pbase + cur[t + 256];
    counts[r0 + t + 256] = h1[t + 256];
    dis[r0 + t + 256] = rsqrtf((float)(h1[t + 256] + 1));
  }
  __syncthreads();
  for (int i = t; i < sz; i += 256) {
    int u = tmp[base + i];
    int p = pbase + atomicAdd(&cur[u & 511], 1);
    col[p] = u >> BKT_SH;
  }
  __syncthreads();
  for (int i = t; i < nrows; i += 256) {
    int cnt = h1[i];
    int c32 = (cnt + 31) & ~31;
    int ps = pbase + cur[i];
    for (int k = cnt; k < c32; ++k) col[ps++] = N;
  }
}

// zero pad row N of both y buffers (row-major [N+1][64] bf16)
__global__ void k_zrow(unsigned short* __restrict__ yA, unsigned short* __restrict__ yB, int N) {
  int t = threadIdx.x;                 // 128 threads
  if (t < 64) yA[(size_t)N * 64 + t] = 0;
  else        yB[(size_t)N * 64 + (t - 64)] = 0;
}

// ============ weight conversion to MFMA-native tiled layouts ============
// W1 [512][256] -> WT1t (BK=32): [kstep16][nsub16][q4][n16][e8], k = kstep*32+q*8+e
__global__ void k_wconv1(const float* __restrict__ W, unsigned short* __restrict__ WT) {
  int idx = blockIdx.x * 256 + threadIdx.x;
  if (idx >= 512 * 256) return;
  int e = idx & 7, n = (idx >> 3) & 15, q = (idx >> 7) & 3;
  int nsub = (idx >> 9) & 15, kstep = idx >> 13;
  int k = kstep * 32 + q * 8 + e;
  int ncol = nsub * 16 + n;
  WT[idx] = f2bf(W[(size_t)k * 256 + ncol]);
}

// W2 [256][64] -> WT2t (BK=64): [kstep4][nsub4][q8][n16][e8]
__global__ void k_wconv2(const float* __restrict__ W, unsigned short* __restrict__ WT) {
  int idx = blockIdx.x * 256 + threadIdx.x;
  if (idx >= 256 * 64) return;
  int e = idx & 7, n = (idx >> 3) & 15, q = (idx >> 7) & 7;
  int nsub = (idx >> 10) & 3, kstep = idx >> 12;
  int k = kstep * 64 + q * 8 + e;
  int ncol = nsub * 16 + n;
  WT[idx] = f2bf(W[(size_t)k * 64 + ncol]);
}

// ============ GEMM1: hid_tiled = relu(x @ W1 + b1), BM=128 BN=256 BK=32, double-buffered ====
// 512 threads = 8 waves (2m x 4n), wave tile 64x64 (4x4 of 16x16x32), 16 K-steps.
// One barrier per iter; X loads for ks+1 issued before MFMA(ks).
__global__ __launch_bounds__(512)
void gemm1_kernel(const float* __restrict__ X, const unsigned short* __restrict__ Bt,
                  const float* __restrict__ bias, unsigned short* __restrict__ outT,
                  int M) {
  __shared__ __align__(16) unsigned short Al[2][4096];   // 8 KB each
  __shared__ __align__(16) unsigned short Bl[2][8192];   // 16 KB each
  const int t = threadIdx.x;
  const int m0 = blockIdx.x * 128;
  const int lane = t & 63;
  const int w = t >> 6;
  const int wm = w >> 2, wn = w & 3;

  // A staging: thread t stages 8 bf16 -> Al elem offset msub*512 + q*128 + m*8
  const int am = t & 15;
  const int aq = (t >> 4) & 3;
  const int amsub = t >> 6;
  const int arow = m0 + amsub * 16 + am;
  const bool ag = arow < M;
  const int aoff = amsub * 512 + aq * 128 + am * 8;

  f32x4 acc[4][4] = {};

  // prologue: stage ks=0
  {
    uint4 vv = {0, 0, 0, 0};
    if (ag) {
      const float* p = X + (size_t)arow * 512 + aq * 8;
      float4 a = *(const float4*)p, b = *(const float4*)(p + 4);
      unsigned short* o = (unsigned short*)&vv;
      o[0] = f2bf(a.x); o[1] = f2bf(a.y); o[2] = f2bf(a.z); o[3] = f2bf(a.w);
      o[4] = f2bf(b.x); o[5] = f2bf(b.y); o[6] = f2bf(b.z); o[7] = f2bf(b.w);
    }
    *(uint4*)&Al[0][aoff] = vv;
    gload16(Bt + (size_t)t * 8,         &Bl[0][t * 8]);
    gload16(Bt + (size_t)(t + 512) * 8, &Bl[0][(t + 512) * 8]);
  }
  __syncthreads();

  int cur = 0;
  for (int ks = 0; ks < 16; ++ks) {
    const bool more = ks < 15;
    // early-issue X loads for ks+1
    float4 xa = {0, 0, 0, 0}, xb = {0, 0, 0, 0};
    if (more && ag) {
      const float* p = X + (size_t)arow * 512 + (ks + 1) * 32 + aq * 8;
      xa = *(const float4*)p;
      xb = *(const float4*)(p + 4);
    }
    // MFMA on buf[cur]
    bf16x8 af[4], bfv[4];
#pragma unroll
    for (int mi = 0; mi < 4; ++mi)
      af[mi] = *(const bf16x8*)&Al[cur][(((wm * 4 + mi) * 4 + (lane >> 4)) * 16 + (lane & 15)) * 8];
#pragma unroll
    for (int ni = 0; ni < 4; ++ni)
      bfv[ni] = *(const bf16x8*)&Bl[cur][(((wn * 4 + ni) * 4 + (lane >> 4)) * 16 + (lane & 15)) * 8];
#pragma unroll
    for (int mi = 0; mi < 4; ++mi)
#pragma unroll
      for (int ni = 0; ni < 4; ++ni)
        acc[mi][ni] = __builtin_amdgcn_mfma_f32_16x16x32_bf16(af[mi], bfv[ni], acc[mi][ni], 0, 0, 0);
    // stage buf[cur^1]
    if (more) {
      uint4 vv = {0, 0, 0, 0};
      if (ag) {
        unsigned short* o = (unsigned short*)&vv;
        o[0] = f2bf(xa.x); o[1] = f2bf(xa.y); o[2] = f2bf(xa.z); o[3] = f2bf(xa.w);
        o[4] = f2bf(xb.x); o[5] = f2bf(xb.y); o[6] = f2bf(xb.z); o[7] = f2bf(xb.w);
      }
      *(uint4*)&Al[cur ^ 1][aoff] = vv;
      const unsigned short* bs = Bt + (size_t)(ks + 1) * 8192;
      gload16(bs + (size_t)t * 8,         &Bl[cur ^ 1][t * 8]);
      gload16(bs + (size_t)(t + 512) * 8, &Bl[cur ^ 1][(t + 512) * 8]);
    }
    __syncthreads();
    cur ^= 1;
  }

  // epilogue: relu + bias, write into GEMM2 A-tiled layout [kstep4][msub8][q8][m16][e8]
  unsigned short* ob = outT + (size_t)blockIdx.x * 32768;
#pragma unroll
  for (int mi = 0; mi < 4; ++mi) {
#pragma unroll
    for (int ni = 0; ni < 4; ++ni) {
      int n = wn * 64 + ni * 16 + (lane & 15);
      float bv = bias[n];
      int kstep = n >> 6, q = (n >> 3) & 7, e = n & 7;
#pragma unroll
      for (int j = 0; j < 4; ++j) {
        int lm = wm * 64 + mi * 16 + (lane >> 4) * 4 + j;
        if (m0 + lm < M) {
          float v = fmaxf(acc[mi][ni][j] + bv, 0.f);
          int msub = lm >> 4, mm = lm & 15;
          ob[((((kstep * 8 + msub) * 8 + q) * 16 + mm) * 8) + e] = f2bf(v);
        }
      }
    }
  }
}

// ============ GEMM2: hb = hid @ W2 + b2 (row-major bf16) and y0 = bf16(dis*h) ============
__global__ __launch_bounds__(256)
void gemm2_kernel(const unsigned short* __restrict__ At, const unsigned short* __restrict__ Bt,
                  const float* __restrict__ bias, const float* __restrict__ dis,
                  unsigned short* __restrict__ hb, unsigned short* __restrict__ y0, int M) {
  __shared__ __align__(16) unsigned short Al[8192];
  __shared__ __align__(16) unsigned short Bl[4096];
  const int t = threadIdx.x;
  const int m0 = blockIdx.x * 128;
  const int lane = t & 63;
  const int w = t >> 6;
  const int wm = w >> 1, wn = w & 1;

  f32x4 acc[4][2] = {};

  const unsigned short* ab = At + (size_t)blockIdx.x * 32768;
  for (int ks = 0; ks < 4; ++ks) {
    const unsigned short* as = ab + ks * 8192;
    gload16(as + (size_t)t * 8,         &Al[t * 8]);
    gload16(as + (size_t)(t + 256) * 8, &Al[(t + 256) * 8]);
    gload16(as + (size_t)(t + 512) * 8, &Al[(t + 512) * 8]);
    gload16(as + (size_t)(t + 768) * 8, &Al[(t + 768) * 8]);
    const unsigned short* bs = Bt + ks * 4096;
    gload16(bs + (size_t)t * 8,         &Bl[t * 8]);
    gload16(bs + (size_t)(t + 256) * 8, &Bl[(t + 256) * 8]);
    __syncthreads();

#pragma unroll
    for (int kk = 0; kk < 2; ++kk) {
      bf16x8 af[4], bfv[2];
#pragma unroll
      for (int mi = 0; mi < 4; ++mi)
        af[mi] = *(const bf16x8*)&Al[((wm * 4 + mi) * 128 + kk * 64 + (lane >> 4) * 16 + (lane & 15)) * 8];
#pragma unroll
      for (int ni = 0; ni < 2; ++ni)
        bfv[ni] = *(const bf16x8*)&Bl[((wn * 2 + ni) * 128 + kk * 64 + (lane >> 4) * 16 + (lane & 15)) * 8];
#pragma unroll
      for (int mi = 0; mi < 4; ++mi)
#pragma unroll
        for (int ni = 0; ni < 2; ++ni)
          acc[mi][ni] = __builtin_amdgcn_mfma_f32_16x16x32_bf16(af[mi], bfv[ni], acc[mi][ni], 0, 0, 0);
    }
    __syncthreads();
  }

#pragma unroll
  for (int mi = 0; mi < 4; ++mi) {
#pragma unroll
    for (int ni = 0; ni < 2; ++ni) {
      int gn = wn * 32 + ni * 16 + (lane & 15);
      float bv = bias[gn];
#pragma unroll
      for (int j = 0; j < 4; ++j) {
        int gm = m0 + wm * 64 + mi * 16 + (lane >> 4) * 4 + j;
        if (gm < M) {
          float v = acc[mi][ni][j] + bv;
          hb[(size_t)gm * 64 + gn] = f2bf(v);
          y0[(size_t)gm * 64 + gn] = f2bf(dis[gm] * v);
        }
      }
    }
  }
}

// ============ PPR diffusion (r7 shape): one wave per dst row, y-trick, padded edges ============
// y = dis .* z, bf16 [N+1][64] (row N zeros). Per iter: 32 edges, group g (8 lanes)
// handles edges 4g..4g+3 via one int4 col load + 4 independent dwordx4 gathers.
template<bool FINAL>
__global__ __launch_bounds__(256)
void prop_kernel(const unsigned short* __restrict__ yin,
                 const unsigned short* __restrict__ hb,
                 void* __restrict__ yout,
                 const int* __restrict__ rowptr, const int* __restrict__ counts,
                 const int* __restrict__ col, const float* __restrict__ dis, int N) {
  int wid = (blockIdx.x * 256 + threadIdx.x) >> 6;
  wid = __builtin_amdgcn_readfirstlane(wid);   // wave-uniform -> scalar loads
  if (wid >= N) return;
  const int lane = threadIdx.x & 63;
  const int g = lane >> 3;
  const int lg = lane & 7;
  const int r = wid;

  const int start = rowptr[r];
  const int cnt = counts[r];
  const int iters = (cnt + 31) >> 5;
  const float dr = dis[r];
  uint4 zs = *(const uint4*)(yin + (size_t)r * 64 + 8 * lg);
  uint4 hr = *(const uint4*)(hb + (size_t)r * 64 + 8 * lg);

  float acc[8] = {0.f, 0.f, 0.f, 0.f, 0.f, 0.f, 0.f, 0.f};
  const int* cp = col + start + 4 * g;
  for (int it = 0; it < iters; ++it, cp += 32) {
    int4 cc = *(const int4*)cp;
    uint4 z0 = *(const uint4*)(yin + (size_t)cc.x * 64 + 8 * lg);
    uint4 z1 = *(const uint4*)(yin + (size_t)cc.y * 64 + 8 * lg);
    uint4 z2 = *(const uint4*)(yin + (size_t)cc.z * 64 + 8 * lg);
    uint4 z3 = *(const uint4*)(yin + (size_t)cc.w * 64 + 8 * lg);
    acc[0] += bflo(z0.x); acc[1] += bfhi(z0.x); acc[2] += bflo(z0.y); acc[3] += bfhi(z0.y);
    acc[4] += bflo(z0.z); acc[5] += bfhi(z0.z); acc[6] += bflo(z0.w); acc[7] += bfhi(z0.w);
    acc[0] += bflo(z1.x); acc[1] += bfhi(z1.x); acc[2] += bflo(z1.y); acc[3] += bfhi(z1.y);
    acc[4] += bflo(z1.z); acc[5] += bfhi(z1.z); acc[6] += bflo(z1.w); acc[7] += bfhi(z1.w);
    acc[0] += bflo(z2.x); acc[1] += bfhi(z2.x); acc[2] += bflo(z2.y); acc[3] += bfhi(z2.y);
    acc[4] += bflo(z2.z); acc[5] += bfhi(z2.z); acc[6] += bflo(z2.w); acc[7] += bfhi(z2.w);
    acc[0] += bflo(z3.x); acc[1] += bfhi(z3.x); acc[2] += bflo(z3.y); acc[3] += bfhi(z3.y);
    acc[4] += bflo(z3.z); acc[5] += bfhi(z3.z); acc[6] += bflo(z3.w); acc[7] += bfhi(z3.w);
  }
#pragma unroll
  for (int k = 0; k < 8; ++k) {
    acc[k] += __shfl_xor(acc[k], 8);
    acc[k] += __shfl_xor(acc[k], 16);
    acc[k] += __shfl_xor(acc[k], 32);
  }

  float selfz[8] = { bflo(zs.x), bfhi(zs.x), bflo(zs.y), bfhi(zs.y),
                     bflo(zs.z), bfhi(zs.z), bflo(zs.w), bfhi(zs.w) };
  float hv[8]    = { bflo(hr.x), bfhi(hr.x), bflo(hr.y), bfhi(hr.y),
                     bflo(hr.z), bfhi(hr.z), bflo(hr.w), bfhi(hr.w) };
  float f[8];
#pragma unroll
  for (int k = 0; k < 8; ++k)
    f[k] = ALPHA_F * hv[k] + (1.f - ALPHA_F) * dr * (acc[k] + selfz[k]);

  if (!FINAL) {
    if (g == 0) {
      uint4 o;
      o.x = (unsigned)f2bf(dr * f[0]) | ((unsigned)f2bf(dr * f[1]) << 16);
      o.y = (unsigned)f2bf(dr * f[2]) | ((unsigned)f2bf(dr * f[3]) << 16);
      o.z = (unsigned)f2bf(dr * f[4]) | ((unsigned)f2bf(dr * f[5]) << 16);
      o.w = (unsigned)f2bf(dr * f[6]) | ((unsigned)f2bf(dr * f[7]) << 16);
      *(uint4*)((unsigned short*)yout + (size_t)r * 64 + 8 * lg) = o;
    }
  } else {
    float m = f[0];
#pragma unroll
    for (int k = 1; k < 8; ++k) m = fmaxf(m, f[k]);
    m = fmaxf(m, __shfl_xor(m, 1));
    m = fmaxf(m, __shfl_xor(m, 2));
    m = fmaxf(m, __shfl_xor(m, 4));
    float s = 0.f;
#pragma unroll
    for (int k = 0; k < 8; ++k) s += __expf(f[k] - m);
    s += __shfl_xor(s, 1);
    s += __shfl_xor(s, 2);
    s += __shfl_xor(s, 4);
    float ls = __logf(s);
    if (g == 0) {
      float* op = (float*)yout + (size_t)r * 64 + 8 * lg;
      *(float4*)op       = make_float4(f[0] - m - ls, f[1] - m - ls, f[2] - m - ls, f[3] - m - ls);
      *(float4*)(op + 4) = make_float4(f[4] - m - ls, f[5] - m - ls, f[6] - m - ls, f[7] - m - ls);
    }
  }
}

extern "C" void kernel_launch(void* const* d_in, const int* in_sizes, int n_in,
                              void* d_out, int out_size, void* d_ws, size_t ws_size,
                              hipStream_t stream) {
  const float* x  = (const float*)d_in[0];
  const int*   ei = (const int*)d_in[1];
  const float* W1 = (const float*)d_in[2];
  const float* b1 = (const float*)d_in[3];
  const float* W2 = (const float*)d_in[4];
  const float* b2 = (const float*)d_in[5];

  const int IN = 512, HID = 256, OUT = 64;
  const int N = in_sizes[0] / IN;
  const int E = in_sizes[1] / 2;
  const int* srcv = ei;
  const int* dstv = ei + E;
  const int NBUCK = (N + (1 << BKT_SH) - 1) >> BKT_SH;
  const int MT = (N + 127) / 128;
  const size_t N1 = (size_t)N + 1;

  char* p = (char*)d_ws;
  auto alloc = [&](size_t bytes) -> void* {
    void* r = (void*)p;
    p += (bytes + 255) & ~(size_t)255;
    return r;
  };
  int*   bhist  = (int*)alloc(256 * 4);
  int*   bbase  = (int*)alloc(256 * 4);
  int*   gcur   = (int*)alloc(256 * 4);
  int*   counts = (int*)alloc((size_t)N * 4);
  float* dis    = (float*)alloc((size_t)N * 4);
  int*   rowptr = (int*)alloc((size_t)N * 4);
  int*   col    = (int*)alloc(((size_t)E + 256 * MAXPAD_PER_BUCKET) * 4);
  unsigned short* WT1t = (unsigned short*)alloc((size_t)IN * HID * 2);
  unsigned short* WT2t = (unsigned short*)alloc((size_t)HID * OUT * 2);
  unsigned short* hb   = (unsigned short*)alloc((size_t)N * OUT * 2);    // bf16 h [N][64]
  unsigned short* yA   = (unsigned short*)alloc(N1 * OUT * 2);           // y [N+1][64]
  // region R: tmp (build, int E) -> hidT (gemm) -> yB (prop)
  size_t hidT_bytes = (size_t)MT * 32768 * 2;
  size_t R_bytes = hidT_bytes;
  if ((size_t)E * 4 > R_bytes) R_bytes = (size_t)E * 4;
  if (N1 * OUT * 2 > R_bytes) R_bytes = N1 * OUT * 2;
  char* R = (char*)alloc(R_bytes);
  int* tmp = (int*)R;
  unsigned short* hidT = (unsigned short*)R;
  unsigned short* yB = (unsigned short*)R;

  hipMemsetAsync(bhist, 0, 256 * 4, stream);

  const int p1blocks = (E + P1_CHUNK - 1) / P1_CHUNK;
  p0_hist<<<p1blocks, 256, 0, stream>>>(dstv, E, bhist);
  p0_scan<<<1, 256, 0, stream>>>(bhist, bbase, gcur);
  p1_scatter<<<p1blocks, 256, 0, stream>>>(srcv, dstv, E, gcur, tmp);
  p2_bucket<<<NBUCK, 256, 0, stream>>>(tmp, bbase, bhist, counts, dis, rowptr, col, N);

  k_wconv1<<<(IN * HID + 255) / 256, 256, 0, stream>>>(W1, WT1t);
  k_wconv2<<<(HID * OUT + 255) / 256, 256, 0, stream>>>(W2, WT2t);

  gemm1_kernel<<<MT, 512, 0, stream>>>(x, WT1t, b1, hidT, N);
  gemm2_kernel<<<MT, 256, 0, stream>>>(hidT, WT2t, b2, dis, hb, yA, N);
  k_zrow<<<1, 128, 0, stream>>>(yA, yB, N);

  const int pblocks = (N + 3) / 4;
  const unsigned short* ycur = yA;
  for (int it = 0; it < KSTEPS - 1; ++it) {
    unsigned short* ynext = (it & 1) ? yA : yB;
    prop_kernel<false><<<pblocks, 256, 0, stream>>>(ycur, hb, ynext, rowptr, counts, col, dis, N);
    ycur = ynext;
  }
  prop_kernel<true><<<pblocks, 256, 0, stream>>>(ycur, hb, d_out, rowptr, counts, col, dis, N);
}